// Round 10
// baseline (229.588 us; speedup 1.0000x reference)
//
#include <hip/hip_runtime.h>

#define BB 2
#define SS 4096
#define DM 768
#define NH 12
#define OUTC 512
#define QSCALE 0.125f

// partial-buffer stage-B geometry (round-6 proven optimum)
#define MCHUNK 256        // s-chunks per batch
#define MCS 16            // s-rows per chunk
// kA geometry
#define JSA 4
#define JWA (DM/JSA)      // 192
// tail geometry
#define JT 64
#define JR (DM/JT)        // 12
// fallback kB geometry (round-1 proven)
#define NCHUNK 128
#define CS 32
#define HPB 3
#define HG (NH/HPB)

// part layout (floats): part[((b*MCHUNK + c)*NH + h)*DM + d]   (round-4 proven)
#define PIDX(b,c,h) (((size_t)((b)*MCHUNK + (c))*NH + (h))*DM)

__device__ __forceinline__ float wave_sum64(float v) {
#pragma unroll
  for (int o = 32; o > 0; o >>= 1) v += __shfl_xor(v, o, 64);
  return v;
}

// Kernel A: per (h,b,js): qg0 = (x[b,0,:]@wqg+bqg)*QSCALE (redundant per js);
// fold wkg into qw[b,h,js-slice] and qb[b,h]. Zero l + done + xw + out0 region.
__global__ __launch_bounds__(256) void kA(const float* __restrict__ x,
    const float* __restrict__ wqg, const float* __restrict__ bqg,
    const float* __restrict__ wkg, const float* __restrict__ bkg,
    float* __restrict__ qw_ws, float* __restrict__ qb_ws,
    float* __restrict__ l_ws, float* __restrict__ xw_ws,
    float* __restrict__ zb /* out0 base: 4608 floats contiguous */,
    int* __restrict__ done) {
  int h = blockIdx.x, b = blockIdx.y, js = blockIdx.z, t = threadIdx.x;
  __shared__ float x0[DM];
  __shared__ float4 red4[16][16];
  __shared__ float qg0[64];
  for (int i = t; i < DM; i += 256) x0[i] = x[(size_t)b*SS*DM + i];
  for (int i = t; i < JWA; i += 256)
    xw_ws[((size_t)b*NH + h)*DM + js*JWA + i] = 0.f;
  if (js == 3 && t < 192) zb[(b*NH + h)*192 + t] = 0.f;   // 24 blk x 192 = 4608
  if (js == 0 && t == 0) { l_ws[b*NH + h] = 0.f; done[b*NH + h] = 0; }
  __syncthreads();
  {
    int cq = t & 15, jg = t >> 4;
    const float4* wq4 = (const float4*)wqg;
    float4 a = {0,0,0,0};
#pragma unroll 8
    for (int jo = 0; jo < 48; ++jo) {
      int j = jg*48 + jo;
      float xv = x0[j];
      float4 wv = wq4[(size_t)j*(DM/4) + h*16 + cq];
      a.x += xv*wv.x; a.y += xv*wv.y; a.z += xv*wv.z; a.w += xv*wv.w;
    }
    red4[jg][cq] = a;
  }
  __syncthreads();
  if (t < 16) {
    float4 a = {0,0,0,0};
#pragma unroll
    for (int jg = 0; jg < 16; ++jg) {
      float4 r = red4[jg][t];
      a.x += r.x; a.y += r.y; a.z += r.z; a.w += r.w;
    }
    float4 bq = ((const float4*)(bqg + h*64))[t];
    a.x = (a.x + bq.x)*QSCALE; a.y = (a.y + bq.y)*QSCALE;
    a.z = (a.z + bq.z)*QSCALE; a.w = (a.w + bq.w)*QSCALE;
    ((float4*)qg0)[t] = a;
  }
  __syncthreads();
  if (js == 0 && t < 64) {
    float v = wave_sum64(qg0[t] * bkg[h*64 + t]);
    if (t == 0) qb_ws[b*NH + h] = v;
  }
  const float4* qg4 = (const float4*)qg0;
  for (int jj = t; jj < JWA; jj += 256) {
    int j = js*JWA + jj;
    const float4* wr = (const float4*)(wkg + (size_t)j*DM + h*64);
    float acc = 0.f;
#pragma unroll
    for (int q = 0; q < 16; ++q) {
      float4 wv = wr[q], qv = qg4[q];
      acc += wv.x*qv.x + wv.y*qv.y + wv.z*qv.z + wv.w*qv.w;
    }
    qw_ws[((size_t)b*NH + h)*DM + j] = acc;
  }
}

// Kernel Bp (round-6 proven): per (chunk,b): 16 rows x 12 heads.
// Phase 1: scores+exp+l(atomic). Phase 2: p-weighted x partial -> PLAIN float4
// stores into private part slot. No xw atomics.
__global__ __launch_bounds__(256) void kBp(const float* __restrict__ x,
    const float* __restrict__ qw_ws, const float* __restrict__ qb_ws,
    float* __restrict__ l_ws, float* __restrict__ part) {
  const int chunk = blockIdx.x, b = blockIdx.y;
  const int t = threadIdx.x, lane = t & 63, w = t >> 6;
  __shared__ alignas(16) float qw[NH*DM];   // 36 KB
  __shared__ float qb[NH];
  __shared__ alignas(16) float pl[MCS*NH];  // 768 B
  __shared__ float lred[4][NH];
  const float4* qwsrc = (const float4*)(qw_ws + (size_t)b*NH*DM);
  float4* qw4s = (float4*)qw;
#pragma unroll
  for (int i = 0; i < 9; ++i) qw4s[t + 256*i] = qwsrc[t + 256*i];
  if (t < NH) qb[t] = qb_ws[b*NH + t];
  __syncthreads();
  const size_t xbase = ((size_t)b*SS + (size_t)chunk*MCS) * DM;
  const float4* x4 = (const float4*)(x + xbase);
  const float4* qw4 = (const float4*)qw;
  const int sl = w*4;
  float acc[4][NH];
#pragma unroll
  for (int si = 0; si < 4; ++si)
#pragma unroll
    for (int hh = 0; hh < NH; ++hh) acc[si][hh] = 0.f;
#pragma unroll
  for (int k = 0; k < 3; ++k) {
    int jq = k*64 + lane;
    float4 xf[4];
#pragma unroll
    for (int si = 0; si < 4; ++si)
      xf[si] = x4[(size_t)(sl + si)*192 + jq];
#pragma unroll
    for (int hh = 0; hh < NH; ++hh) {
      float4 qv = qw4[hh*192 + jq];
#pragma unroll
      for (int si = 0; si < 4; ++si)
        acc[si][hh] += xf[si].x*qv.x + xf[si].y*qv.y + xf[si].z*qv.z + xf[si].w*qv.w;
    }
  }
  float lacc = 0.f, preg = 0.f;
#pragma unroll
  for (int si = 0; si < 4; ++si)
#pragma unroll
    for (int hh = 0; hh < NH; ++hh) {
      float r = wave_sum64(acc[si][hh]);
      float pp = __expf(r + qb[hh]);
      if (lane == hh) lacc += pp;
      if (lane == si*NH + hh) preg = pp;
    }
  if (lane < 4*NH) pl[sl*NH + lane] = preg;   // rows sl..sl+3, heads 0..11
  if (lane < NH) lred[w][lane] = lacc;
  __syncthreads();
  if (t < NH)
    atomicAdd(&l_ws[b*NH + t], lred[0][t] + lred[1][t] + lred[2][t] + lred[3][t]);
  // phase 2: partial xw for this chunk, x rows L1-hot from phase 1
  if (t < 192) {
    float4 a2[NH];
#pragma unroll
    for (int hh = 0; hh < NH; ++hh) a2[hh] = make_float4(0.f,0.f,0.f,0.f);
    for (int s = 0; s < MCS; ++s) {
      float4 xv = x4[s*192 + t];
      const float4* p4 = (const float4*)(pl + s*NH);
      float4 p0 = p4[0], p1 = p4[1], p2 = p4[2];
      float pv[NH] = {p0.x,p0.y,p0.z,p0.w, p1.x,p1.y,p1.z,p1.w, p2.x,p2.y,p2.z,p2.w};
#pragma unroll
      for (int hh = 0; hh < NH; ++hh) {
        a2[hh].x += pv[hh]*xv.x; a2[hh].y += pv[hh]*xv.y;
        a2[hh].z += pv[hh]*xv.z; a2[hh].w += pv[hh]*xv.w;
      }
    }
    float4* pdst = (float4*)part;
    const size_t base = PIDX(b, chunk, 0)/4;      // contiguous 36 KB per chunk
#pragma unroll
    for (int hh = 0; hh < NH; ++hh)
      pdst[base + (size_t)hh*192 + t] = a2[hh];
  }
}

// Kernel RE: kR + fused E1 via last-arriving-block. Grid (NH, BB, 32).
// Each block sums 32 chunks of a 192-float slice into xw (device atomics),
// then bumps done[b*NH+h]; the 32nd block performs E1 for that (b,h):
// normalize xw by l, apply wvg, complete-write out0, zero zbuf segment.
__global__ __launch_bounds__(256) void kRE(const float* __restrict__ part,
    float* __restrict__ xw_ws, const float* __restrict__ l_ws,
    const float* __restrict__ wvg, const float* __restrict__ bvg,
    float* __restrict__ out0_ws, float* __restrict__ zbuf,
    int* __restrict__ done) {
  int h = blockIdx.x, b = blockIdx.y, z = blockIdx.z, t = threadIdx.x;
  int js = z >> 3, cs = z & 7;
  __shared__ float xws[DM];
  __shared__ float4 red4[16][16];
  __shared__ int lastflag;
  if (t < 192) {
    const float* src = part + PIDX(b, cs*32, h) + js*192 + t;
    float s0 = 0.f, s1 = 0.f, s2 = 0.f, s3 = 0.f;
    const size_t cstride = (size_t)NH*DM;
#pragma unroll
    for (int c = 0; c < 32; c += 4) {
      s0 += src[(size_t)(c+0)*cstride];
      s1 += src[(size_t)(c+1)*cstride];
      s2 += src[(size_t)(c+2)*cstride];
      s3 += src[(size_t)(c+3)*cstride];
    }
    atomicAdd(&xw_ws[((size_t)b*NH + h)*DM + js*192 + t], (s0+s1)+(s2+s3));
  }
  __threadfence();          // release: xw atomics globally visible before counter
  __syncthreads();
  if (t == 0) lastflag = (atomicAdd(&done[b*NH + h], 1) == 31) ? 1 : 0;
  __syncthreads();
  if (!lastflag) return;
  __threadfence();          // acquire side: order subsequent xw loads

  // ---- fused E1 for this (b,h) ----
  int bid = b*NH + h;
  if (t < 128) zbuf[bid*128 + t] = 0.f;   // zero attnraw+pooledraw segment
  float inv = 1.f / l_ws[bid];
#pragma unroll
  for (int i = 0; i < 3; ++i) {
    int j = t + 256*i;
    xws[j] = xw_ws[((size_t)b*NH + h)*DM + j] * inv;
  }
  __syncthreads();
  {
    int cq = t & 15, jg = t >> 4;
    const float4* wv4 = (const float4*)wvg;
    float4 a = {0,0,0,0};
#pragma unroll 8
    for (int jo = 0; jo < 48; ++jo) {
      int j = jg*48 + jo;
      float xv = xws[j];
      float4 wv = wv4[(size_t)j*(DM/4) + h*16 + cq];
      a.x += xv*wv.x; a.y += xv*wv.y; a.z += xv*wv.z; a.w += xv*wv.w;
    }
    red4[jg][cq] = a;
  }
  __syncthreads();
  if (t < 16) {
    float4 a = {0,0,0,0};
#pragma unroll
    for (int jg = 0; jg < 16; ++jg) {
      float4 r = red4[jg][t];
      a.x += r.x; a.y += r.y; a.z += r.z; a.w += r.w;
    }
    float4 bv = ((const float4*)(bvg + h*64))[t];
    a.x += bv.x; a.y += bv.y; a.z += bv.z; a.w += bv.w;
    ((float4*)(out0_ws + (size_t)b*DM + h*64))[t] = a;
  }
}

// Kernel E1 (fallback path): normalize xw by l, apply wvg, complete-write out0.
// Also zeroes attnraw+pooledraw (zbuf, 3072 floats contiguous).
__global__ __launch_bounds__(256) void kE1(const float* __restrict__ xw_ws,
    const float* __restrict__ l_ws, const float* __restrict__ wvg,
    const float* __restrict__ bvg, float* __restrict__ out0_ws,
    float* __restrict__ zbuf) {
  int h = blockIdx.x, b = blockIdx.y, t = threadIdx.x;
  __shared__ float xws[DM];
  __shared__ float4 red4[16][16];
  int bid = b*NH + h;
  if (t < 128) zbuf[bid*128 + t] = 0.f;
  float inv = 1.f / l_ws[bid];
#pragma unroll
  for (int i = 0; i < 3; ++i) {
    int j = t + 256*i;
    xws[j] = xw_ws[((size_t)b*NH + h)*DM + j] * inv;
  }
  __syncthreads();
  {
    int cq = t & 15, jg = t >> 4;
    const float4* wv4 = (const float4*)wvg;
    float4 a = {0,0,0,0};
#pragma unroll 8
    for (int jo = 0; jo < 48; ++jo) {
      int j = jg*48 + jo;
      float xv = xws[j];
      float4 wv = wv4[(size_t)j*(DM/4) + h*16 + cq];
      a.x += xv*wv.x; a.y += xv*wv.y; a.z += xv*wv.z; a.w += xv*wv.w;
    }
    red4[jg][cq] = a;
  }
  __syncthreads();
  if (t < 16) {
    float4 a = {0,0,0,0};
#pragma unroll
    for (int jg = 0; jg < 16; ++jg) {
      float4 r = red4[jg][t];
      a.x += r.x; a.y += r.y; a.z += r.z; a.w += r.w;
    }
    float4 bv = ((const float4*)(bvg + h*64))[t];
    a.x += bv.x; a.y += bv.y; a.z += bv.z; a.w += bv.w;
    ((float4*)(out0_ws + (size_t)b*DM + h*64))[t] = a;
  }
}

// Tail matvec (768x768), j-split, atomic accumulation, both batches fused.
__global__ __launch_bounds__(192) void kT(const float* __restrict__ inraw,
    const float* __restrict__ bias, const float* __restrict__ W,
    float* __restrict__ outacc) {
  int jb = blockIdx.x, t = threadIdx.x;
  __shared__ float xs[2][JR];
  int j0 = jb*JR;
  if (t < 2*JR) {
    int bb = t / JR, jj = t % JR;
    float v = inraw[bb*DM + j0 + jj];
    if (bias) v += bias[j0 + jj];
    xs[bb][jj] = v;
  }
  __syncthreads();
  float4 a0 = {0,0,0,0}, a1 = {0,0,0,0};
  const float4* W4 = (const float4*)W;
#pragma unroll
  for (int jj = 0; jj < JR; ++jj) {
    float4 wv = W4[(size_t)(j0 + jj)*192 + t];
    float s0 = xs[0][jj], s1 = xs[1][jj];
    a0.x += s0*wv.x; a0.y += s0*wv.y; a0.z += s0*wv.z; a0.w += s0*wv.w;
    a1.x += s1*wv.x; a1.y += s1*wv.y; a1.z += s1*wv.z; a1.w += s1*wv.w;
  }
  int c = t*4;
  atomicAdd(&outacc[c+0], a0.x); atomicAdd(&outacc[c+1], a0.y);
  atomicAdd(&outacc[c+2], a0.z); atomicAdd(&outacc[c+3], a0.w);
  atomicAdd(&outacc[DM+c+0], a1.x); atomicAdd(&outacc[DM+c+1], a1.y);
  atomicAdd(&outacc[DM+c+2], a1.z); atomicAdd(&outacc[DM+c+3], a1.w);
}

// Final: out[b][tile*64+c] = tanh(pooledraw[b]+bp) . wfc[:,c] + bfc[c], complete write.
__global__ __launch_bounds__(256) void kT3(const float* __restrict__ pooledraw,
    const float* __restrict__ bp, const float* __restrict__ wfc,
    const float* __restrict__ bfc, float* __restrict__ out) {
  int tile = blockIdx.x, b = blockIdx.y, t = threadIdx.x;
  __shared__ float pls[DM];
  __shared__ float4 red4[16][16];
  for (int i = t; i < DM; i += 256) pls[i] = tanhf(pooledraw[b*DM + i] + bp[i]);
  __syncthreads();
  {
    int cq = t & 15, jg = t >> 4;
    const float4* w4 = (const float4*)wfc;
    float4 a = {0,0,0,0};
#pragma unroll 8
    for (int jo = 0; jo < 48; ++jo) {
      int j = jg*48 + jo;
      float pv = pls[j];
      float4 wv = w4[(size_t)j*(OUTC/4) + tile*16 + cq];
      a.x += pv*wv.x; a.y += pv*wv.y; a.z += pv*wv.z; a.w += pv*wv.w;
    }
    red4[jg][cq] = a;
  }
  __syncthreads();
  if (t < 16) {
    float4 a = {0,0,0,0};
#pragma unroll
    for (int jg = 0; jg < 16; ++jg) {
      float4 r = red4[jg][t];
      a.x += r.x; a.y += r.y; a.z += r.z; a.w += r.w;
    }
    float4 bf = ((const float4*)(bfc + tile*64))[t];
    a.x += bf.x; a.y += bf.y; a.z += bf.z; a.w += bf.w;
    ((float4*)(out + (size_t)b*OUTC + tile*64))[t] = a;
  }
}

// ============ fallback stage-B (round-1 proven, used if ws too small) ============

__global__ __launch_bounds__(256) void kB(const float* __restrict__ x,
    const float* __restrict__ qw_ws, const float* __restrict__ qb_ws,
    float* __restrict__ l_ws, float* __restrict__ xw_ws) {
  int chunk = blockIdx.x, b = blockIdx.y, h0 = blockIdx.z * HPB;
  int t = threadIdx.x, lane = t & 63, w = t >> 6;
  __shared__ alignas(16) float qw[HPB*DM];
  __shared__ float qb[HPB];
  __shared__ alignas(16) float pl[CS*HPB];
  for (int i = t; i < HPB*DM; i += 256) qw[i] = qw_ws[((size_t)b*NH + h0)*DM + i];
  if (t < HPB) qb[t] = qb_ws[b*NH + h0 + t];
  __syncthreads();
  const size_t xbase = ((size_t)b*SS + chunk*CS) * DM;
  const float4* x4 = (const float4*)(x + xbase);
  const float4* qw4 = (const float4*)qw;
  float lacc = 0.f;
  for (int batch = 0; batch < 2; ++batch) {
    int sl = w*8 + batch*4;
    float acc[4][HPB];
#pragma unroll
    for (int si = 0; si < 4; ++si)
#pragma unroll
      for (int hh = 0; hh < HPB; ++hh) acc[si][hh] = 0.f;
#pragma unroll
    for (int k = 0; k < 3; ++k) {
      int jq = k*64 + lane;
      float4 xf[4];
#pragma unroll
      for (int si = 0; si < 4; ++si)
        xf[si] = x4[(size_t)(sl + si)*192 + jq];
#pragma unroll
      for (int hh = 0; hh < HPB; ++hh) {
        float4 qv = qw4[hh*192 + jq];
#pragma unroll
        for (int si = 0; si < 4; ++si)
          acc[si][hh] += xf[si].x*qv.x + xf[si].y*qv.y + xf[si].z*qv.z + xf[si].w*qv.w;
      }
    }
    float preg = 0.f;
#pragma unroll
    for (int si = 0; si < 4; ++si)
#pragma unroll
      for (int hh = 0; hh < HPB; ++hh) {
        float r = wave_sum64(acc[si][hh]);
        float pp = __expf(r + qb[hh]);
        if (lane == hh) lacc += pp;
        if (lane == si*HPB + hh) preg = pp;
      }
    if (lane < 4*HPB) pl[(sl + lane/HPB)*HPB + (lane % HPB)] = preg;
  }
  if (lane < HPB) atomicAdd(&l_ws[b*NH + h0 + lane], lacc);
  __syncthreads();
  float a2[HPB][3];
#pragma unroll
  for (int hh = 0; hh < HPB; ++hh)
#pragma unroll
    for (int i = 0; i < 3; ++i) a2[hh][i] = 0.f;
  for (int s = 0; s < CS; ++s) {
    float pv[HPB];
#pragma unroll
    for (int hh = 0; hh < HPB; ++hh) pv[hh] = pl[s*HPB + hh];
    float xv[3];
#pragma unroll
    for (int i = 0; i < 3; ++i)
      xv[i] = x[xbase + (size_t)s*DM + t + 256*i];
#pragma unroll
    for (int hh = 0; hh < HPB; ++hh)
#pragma unroll
      for (int i = 0; i < 3; ++i) a2[hh][i] += pv[hh]*xv[i];
  }
#pragma unroll
  for (int hh = 0; hh < HPB; ++hh)
#pragma unroll
    for (int i = 0; i < 3; ++i)
      atomicAdd(&xw_ws[((size_t)b*NH + h0 + hh)*DM + t + 256*i], a2[hh][i]);
}

extern "C" void kernel_launch(void* const* d_in, const int* in_sizes, int n_in,
                              void* d_out, int out_size, void* d_ws, size_t ws_size,
                              hipStream_t stream) {
  const float* x   = (const float*)d_in[0];
  const float* wqg = (const float*)d_in[7];
  const float* bqg = (const float*)d_in[8];
  const float* wkg = (const float*)d_in[9];
  const float* bkg = (const float*)d_in[10];
  const float* wvg = (const float*)d_in[11];
  const float* bvg = (const float*)d_in[12];
  const float* wo  = (const float*)d_in[13];
  const float* bo  = (const float*)d_in[14];
  const float* wp  = (const float*)d_in[15];
  const float* bp  = (const float*)d_in[16];
  const float* wfc = (const float*)d_in[17];
  const float* bfc = (const float*)d_in[18];

  float* ws        = (float*)d_ws;
  float* qw        = ws;             // 18432
  float* qb        = ws + 18432;     // 24
  float* l         = ws + 18456;     // 24
  float* xw        = ws + 18480;     // 18432
  float* out0      = ws + 36912;     // 1536
  float* attnraw   = ws + 38448;     // 1536
  float* pooledraw = ws + 39984;     // 1536  (out0..pooledraw contiguous = 4608)
  int*   done      = (int*)(ws + 41520);   // 24 ints (+pad to 32)
  float* part      = ws + 41552;     // 4,718,592 floats (18.9 MB), float4-aligned

  const size_t need_bytes = (size_t)(41552 + (size_t)BB*NH*MCHUNK*DM) * sizeof(float);

  kA<<<dim3(NH, BB, JSA), 256, 0, stream>>>(x, wqg, bqg, wkg, bkg, qw, qb, l, xw,
                                            out0, done);
  if (ws_size >= need_bytes) {
    kBp<<<dim3(MCHUNK, BB), 256, 0, stream>>>(x, qw, qb, l, part);
    kRE<<<dim3(NH, BB, 32), 256, 0, stream>>>(part, xw, l, wvg, bvg, out0,
                                              attnraw, done);
  } else {
    kB <<<dim3(NCHUNK, BB, HG), 256, 0, stream>>>(x, qw, qb, l, xw);
    kE1<<<dim3(NH, BB), 256, 0, stream>>>(xw, l, wvg, bvg, out0, attnraw);
  }
  kT <<<dim3(JT),    192, 0, stream>>>(out0, nullptr, wo, attnraw);
  kT <<<dim3(JT),    192, 0, stream>>>(attnraw, bo, wp, pooledraw);
  kT3<<<dim3(8, BB), 256, 0, stream>>>(pooledraw, bp, wfc, bfc, (float*)d_out);
}

// Round 11
// 183.028 us; speedup vs baseline: 1.2544x; 1.2544x over previous
//
#include <hip/hip_runtime.h>

#define BB 2
#define SS 4096
#define DM 768
#define NH 12
#define OUTC 512
#define QSCALE 0.125f

// partial-buffer stage-B geometry (round-6 proven optimum)
#define MCHUNK 256        // s-chunks per batch
#define MCS 16            // s-rows per chunk
// kA geometry
#define JSA 4
#define JWA (DM/JSA)      // 192
// tail geometry: 128 blocks x 6 rows (halved serial chain vs JT=64)
#define JT 128
#define JR (DM/JT)        // 6
// fallback kB geometry (round-1 proven)
#define NCHUNK 128
#define CS 32
#define HPB 3
#define HG (NH/HPB)

// part layout (floats): part[((b*MCHUNK + c)*NH + h)*DM + d]   (round-4 proven)
#define PIDX(b,c,h) (((size_t)((b)*MCHUNK + (c))*NH + (h))*DM)

__device__ __forceinline__ float wave_sum64(float v) {
#pragma unroll
  for (int o = 32; o > 0; o >>= 1) v += __shfl_xor(v, o, 64);
  return v;
}

// Kernel A: per (h,b,js): qg0 = (x[b,0,:]@wqg+bqg)*QSCALE (redundant per js);
// fold wkg into qw[b,h,js-slice] and qb[b,h]. Zero l + xw + out0..pooledraw region.
__global__ __launch_bounds__(256) void kA(const float* __restrict__ x,
    const float* __restrict__ wqg, const float* __restrict__ bqg,
    const float* __restrict__ wkg, const float* __restrict__ bkg,
    float* __restrict__ qw_ws, float* __restrict__ qb_ws,
    float* __restrict__ l_ws, float* __restrict__ xw_ws,
    float* __restrict__ zb /* out0 base: 4608 floats contiguous */) {
  int h = blockIdx.x, b = blockIdx.y, js = blockIdx.z, t = threadIdx.x;
  __shared__ float x0[DM];
  __shared__ float4 red4[16][16];
  __shared__ float qg0[64];
  for (int i = t; i < DM; i += 256) x0[i] = x[(size_t)b*SS*DM + i];
  for (int i = t; i < JWA; i += 256)
    xw_ws[((size_t)b*NH + h)*DM + js*JWA + i] = 0.f;
  if (js == 3 && t < 192) zb[(b*NH + h)*192 + t] = 0.f;   // 24 blk x 192 = 4608
  if (js == 0 && t == 0) l_ws[b*NH + h] = 0.f;
  __syncthreads();
  {
    int cq = t & 15, jg = t >> 4;
    const float4* wq4 = (const float4*)wqg;
    float4 a = {0,0,0,0};
#pragma unroll 8
    for (int jo = 0; jo < 48; ++jo) {
      int j = jg*48 + jo;
      float xv = x0[j];
      float4 wv = wq4[(size_t)j*(DM/4) + h*16 + cq];
      a.x += xv*wv.x; a.y += xv*wv.y; a.z += xv*wv.z; a.w += xv*wv.w;
    }
    red4[jg][cq] = a;
  }
  __syncthreads();
  if (t < 16) {
    float4 a = {0,0,0,0};
#pragma unroll
    for (int jg = 0; jg < 16; ++jg) {
      float4 r = red4[jg][t];
      a.x += r.x; a.y += r.y; a.z += r.z; a.w += r.w;
    }
    float4 bq = ((const float4*)(bqg + h*64))[t];
    a.x = (a.x + bq.x)*QSCALE; a.y = (a.y + bq.y)*QSCALE;
    a.z = (a.z + bq.z)*QSCALE; a.w = (a.w + bq.w)*QSCALE;
    ((float4*)qg0)[t] = a;
  }
  __syncthreads();
  if (js == 0 && t < 64) {
    float v = wave_sum64(qg0[t] * bkg[h*64 + t]);
    if (t == 0) qb_ws[b*NH + h] = v;
  }
  const float4* qg4 = (const float4*)qg0;
  for (int jj = t; jj < JWA; jj += 256) {
    int j = js*JWA + jj;
    const float4* wr = (const float4*)(wkg + (size_t)j*DM + h*64);
    float acc = 0.f;
#pragma unroll
    for (int q = 0; q < 16; ++q) {
      float4 wv = wr[q], qv = qg4[q];
      acc += wv.x*qv.x + wv.y*qv.y + wv.z*qv.z + wv.w*qv.w;
    }
    qw_ws[((size_t)b*NH + h)*DM + j] = acc;
  }
}

// Kernel Bp (round-6 proven): per (chunk,b): 16 rows x 12 heads.
// Phase 1: scores+exp+l(atomic). Phase 2: p-weighted x partial -> PLAIN float4
// stores into private part slot. No xw atomics.
__global__ __launch_bounds__(256) void kBp(const float* __restrict__ x,
    const float* __restrict__ qw_ws, const float* __restrict__ qb_ws,
    float* __restrict__ l_ws, float* __restrict__ part) {
  const int chunk = blockIdx.x, b = blockIdx.y;
  const int t = threadIdx.x, lane = t & 63, w = t >> 6;
  __shared__ alignas(16) float qw[NH*DM];   // 36 KB
  __shared__ float qb[NH];
  __shared__ alignas(16) float pl[MCS*NH];  // 768 B
  __shared__ float lred[4][NH];
  const float4* qwsrc = (const float4*)(qw_ws + (size_t)b*NH*DM);
  float4* qw4s = (float4*)qw;
#pragma unroll
  for (int i = 0; i < 9; ++i) qw4s[t + 256*i] = qwsrc[t + 256*i];
  if (t < NH) qb[t] = qb_ws[b*NH + t];
  __syncthreads();
  const size_t xbase = ((size_t)b*SS + (size_t)chunk*MCS) * DM;
  const float4* x4 = (const float4*)(x + xbase);
  const float4* qw4 = (const float4*)qw;
  const int sl = w*4;
  float acc[4][NH];
#pragma unroll
  for (int si = 0; si < 4; ++si)
#pragma unroll
    for (int hh = 0; hh < NH; ++hh) acc[si][hh] = 0.f;
#pragma unroll
  for (int k = 0; k < 3; ++k) {
    int jq = k*64 + lane;
    float4 xf[4];
#pragma unroll
    for (int si = 0; si < 4; ++si)
      xf[si] = x4[(size_t)(sl + si)*192 + jq];
#pragma unroll
    for (int hh = 0; hh < NH; ++hh) {
      float4 qv = qw4[hh*192 + jq];
#pragma unroll
      for (int si = 0; si < 4; ++si)
        acc[si][hh] += xf[si].x*qv.x + xf[si].y*qv.y + xf[si].z*qv.z + xf[si].w*qv.w;
    }
  }
  float lacc = 0.f, preg = 0.f;
#pragma unroll
  for (int si = 0; si < 4; ++si)
#pragma unroll
    for (int hh = 0; hh < NH; ++hh) {
      float r = wave_sum64(acc[si][hh]);
      float pp = __expf(r + qb[hh]);
      if (lane == hh) lacc += pp;
      if (lane == si*NH + hh) preg = pp;
    }
  if (lane < 4*NH) pl[sl*NH + lane] = preg;   // rows sl..sl+3, heads 0..11
  if (lane < NH) lred[w][lane] = lacc;
  __syncthreads();
  if (t < NH)
    atomicAdd(&l_ws[b*NH + t], lred[0][t] + lred[1][t] + lred[2][t] + lred[3][t]);
  // phase 2: partial xw for this chunk, x rows L1-hot from phase 1
  if (t < 192) {
    float4 a2[NH];
#pragma unroll
    for (int hh = 0; hh < NH; ++hh) a2[hh] = make_float4(0.f,0.f,0.f,0.f);
    for (int s = 0; s < MCS; ++s) {
      float4 xv = x4[s*192 + t];
      const float4* p4 = (const float4*)(pl + s*NH);
      float4 p0 = p4[0], p1 = p4[1], p2 = p4[2];
      float pv[NH] = {p0.x,p0.y,p0.z,p0.w, p1.x,p1.y,p1.z,p1.w, p2.x,p2.y,p2.z,p2.w};
#pragma unroll
      for (int hh = 0; hh < NH; ++hh) {
        a2[hh].x += pv[hh]*xv.x; a2[hh].y += pv[hh]*xv.y;
        a2[hh].z += pv[hh]*xv.z; a2[hh].w += pv[hh]*xv.w;
      }
    }
    float4* pdst = (float4*)part;
    const size_t base = PIDX(b, chunk, 0)/4;      // contiguous 36 KB per chunk
#pragma unroll
    for (int hh = 0; hh < NH; ++hh)
      pdst[base + (size_t)hh*192 + t] = a2[hh];
  }
}

// Kernel R: parallel chunk-reduction of part into xw. Grid (NH, BB, 32):
// z = js*8 + cs; each block sums 32 chunks of a 192-float slice, one atomicAdd/elem.
__global__ __launch_bounds__(256) void kR(const float* __restrict__ part,
    float* __restrict__ xw_ws) {
  int h = blockIdx.x, b = blockIdx.y, z = blockIdx.z, t = threadIdx.x;
  int js = z >> 3, cs = z & 7;
  if (t < 192) {
    const float* src = part + PIDX(b, cs*32, h) + js*192 + t;
    float s0 = 0.f, s1 = 0.f, s2 = 0.f, s3 = 0.f;
    const size_t cstride = (size_t)NH*DM;
#pragma unroll
    for (int c = 0; c < 32; c += 4) {
      s0 += src[(size_t)(c+0)*cstride];
      s1 += src[(size_t)(c+1)*cstride];
      s2 += src[(size_t)(c+2)*cstride];
      s3 += src[(size_t)(c+3)*cstride];
    }
    atomicAdd(&xw_ws[((size_t)b*NH + h)*DM + js*192 + t], (s0+s1)+(s2+s3));
  }
}

// Kernel E1 (round-1 proven): normalize xw by l, apply wvg, complete-write out0.
// Also zeroes attnraw+pooledraw (zbuf, 3072 floats contiguous).
__global__ __launch_bounds__(256) void kE1(const float* __restrict__ xw_ws,
    const float* __restrict__ l_ws, const float* __restrict__ wvg,
    const float* __restrict__ bvg, float* __restrict__ out0_ws,
    float* __restrict__ zbuf) {
  int h = blockIdx.x, b = blockIdx.y, t = threadIdx.x;
  __shared__ float xws[DM];
  __shared__ float4 red4[16][16];
  int bid = b*NH + h;
  if (t < 128) zbuf[bid*128 + t] = 0.f;
  float inv = 1.f / l_ws[bid];
#pragma unroll
  for (int i = 0; i < 3; ++i) {
    int j = t + 256*i;
    xws[j] = xw_ws[((size_t)b*NH + h)*DM + j] * inv;
  }
  __syncthreads();
  {
    int cq = t & 15, jg = t >> 4;
    const float4* wv4 = (const float4*)wvg;
    float4 a = {0,0,0,0};
#pragma unroll 8
    for (int jo = 0; jo < 48; ++jo) {
      int j = jg*48 + jo;
      float xv = xws[j];
      float4 wv = wv4[(size_t)j*(DM/4) + h*16 + cq];
      a.x += xv*wv.x; a.y += xv*wv.y; a.z += xv*wv.z; a.w += xv*wv.w;
    }
    red4[jg][cq] = a;
  }
  __syncthreads();
  if (t < 16) {
    float4 a = {0,0,0,0};
#pragma unroll
    for (int jg = 0; jg < 16; ++jg) {
      float4 r = red4[jg][t];
      a.x += r.x; a.y += r.y; a.z += r.z; a.w += r.w;
    }
    float4 bv = ((const float4*)(bvg + h*64))[t];
    a.x += bv.x; a.y += bv.y; a.z += bv.z; a.w += bv.w;
    ((float4*)(out0_ws + (size_t)b*DM + h*64))[t] = a;
  }
}

// Tail matvec (768x768), j-split 128-way (6 rows/block), atomic accumulation,
// both batches fused.
__global__ __launch_bounds__(192) void kT(const float* __restrict__ inraw,
    const float* __restrict__ bias, const float* __restrict__ W,
    float* __restrict__ outacc) {
  int jb = blockIdx.x, t = threadIdx.x;
  __shared__ float xs[2][JR];
  int j0 = jb*JR;
  if (t < 2*JR) {
    int bb = t / JR, jj = t % JR;
    float v = inraw[bb*DM + j0 + jj];
    if (bias) v += bias[j0 + jj];
    xs[bb][jj] = v;
  }
  __syncthreads();
  float4 a0 = {0,0,0,0}, a1 = {0,0,0,0};
  const float4* W4 = (const float4*)W;
#pragma unroll
  for (int jj = 0; jj < JR; ++jj) {
    float4 wv = W4[(size_t)(j0 + jj)*192 + t];
    float s0 = xs[0][jj], s1 = xs[1][jj];
    a0.x += s0*wv.x; a0.y += s0*wv.y; a0.z += s0*wv.z; a0.w += s0*wv.w;
    a1.x += s1*wv.x; a1.y += s1*wv.y; a1.z += s1*wv.z; a1.w += s1*wv.w;
  }
  int c = t*4;
  atomicAdd(&outacc[c+0], a0.x); atomicAdd(&outacc[c+1], a0.y);
  atomicAdd(&outacc[c+2], a0.z); atomicAdd(&outacc[c+3], a0.w);
  atomicAdd(&outacc[DM+c+0], a1.x); atomicAdd(&outacc[DM+c+1], a1.y);
  atomicAdd(&outacc[DM+c+2], a1.z); atomicAdd(&outacc[DM+c+3], a1.w);
}

// Final: out[b][tile*64+c] = tanh(pooledraw[b]+bp) . wfc[:,c] + bfc[c], complete write.
__global__ __launch_bounds__(256) void kT3(const float* __restrict__ pooledraw,
    const float* __restrict__ bp, const float* __restrict__ wfc,
    const float* __restrict__ bfc, float* __restrict__ out) {
  int tile = blockIdx.x, b = blockIdx.y, t = threadIdx.x;
  __shared__ float pls[DM];
  __shared__ float4 red4[16][16];
  for (int i = t; i < DM; i += 256) pls[i] = tanhf(pooledraw[b*DM + i] + bp[i]);
  __syncthreads();
  {
    int cq = t & 15, jg = t >> 4;
    const float4* w4 = (const float4*)wfc;
    float4 a = {0,0,0,0};
#pragma unroll 8
    for (int jo = 0; jo < 48; ++jo) {
      int j = jg*48 + jo;
      float pv = pls[j];
      float4 wv = w4[(size_t)j*(OUTC/4) + tile*16 + cq];
      a.x += pv*wv.x; a.y += pv*wv.y; a.z += pv*wv.z; a.w += pv*wv.w;
    }
    red4[jg][cq] = a;
  }
  __syncthreads();
  if (t < 16) {
    float4 a = {0,0,0,0};
#pragma unroll
    for (int jg = 0; jg < 16; ++jg) {
      float4 r = red4[jg][t];
      a.x += r.x; a.y += r.y; a.z += r.z; a.w += r.w;
    }
    float4 bf = ((const float4*)(bfc + tile*64))[t];
    a.x += bf.x; a.y += bf.y; a.z += bf.z; a.w += bf.w;
    ((float4*)(out + (size_t)b*OUTC + tile*64))[t] = a;
  }
}

// ============ fallback stage-B (round-1 proven, used if ws too small) ============

__global__ __launch_bounds__(256) void kB(const float* __restrict__ x,
    const float* __restrict__ qw_ws, const float* __restrict__ qb_ws,
    float* __restrict__ l_ws, float* __restrict__ xw_ws) {
  int chunk = blockIdx.x, b = blockIdx.y, h0 = blockIdx.z * HPB;
  int t = threadIdx.x, lane = t & 63, w = t >> 6;
  __shared__ alignas(16) float qw[HPB*DM];
  __shared__ float qb[HPB];
  __shared__ alignas(16) float pl[CS*HPB];
  for (int i = t; i < HPB*DM; i += 256) qw[i] = qw_ws[((size_t)b*NH + h0)*DM + i];
  if (t < HPB) qb[t] = qb_ws[b*NH + h0 + t];
  __syncthreads();
  const size_t xbase = ((size_t)b*SS + chunk*CS) * DM;
  const float4* x4 = (const float4*)(x + xbase);
  const float4* qw4 = (const float4*)qw;
  float lacc = 0.f;
  for (int batch = 0; batch < 2; ++batch) {
    int sl = w*8 + batch*4;
    float acc[4][HPB];
#pragma unroll
    for (int si = 0; si < 4; ++si)
#pragma unroll
      for (int hh = 0; hh < HPB; ++hh) acc[si][hh] = 0.f;
#pragma unroll
    for (int k = 0; k < 3; ++k) {
      int jq = k*64 + lane;
      float4 xf[4];
#pragma unroll
      for (int si = 0; si < 4; ++si)
        xf[si] = x4[(size_t)(sl + si)*192 + jq];
#pragma unroll
      for (int hh = 0; hh < HPB; ++hh) {
        float4 qv = qw4[hh*192 + jq];
#pragma unroll
        for (int si = 0; si < 4; ++si)
          acc[si][hh] += xf[si].x*qv.x + xf[si].y*qv.y + xf[si].z*qv.z + xf[si].w*qv.w;
      }
    }
    float preg = 0.f;
#pragma unroll
    for (int si = 0; si < 4; ++si)
#pragma unroll
      for (int hh = 0; hh < HPB; ++hh) {
        float r = wave_sum64(acc[si][hh]);
        float pp = __expf(r + qb[hh]);
        if (lane == hh) lacc += pp;
        if (lane == si*HPB + hh) preg = pp;
      }
    if (lane < 4*HPB) pl[(sl + lane/HPB)*HPB + (lane % HPB)] = preg;
  }
  if (lane < HPB) atomicAdd(&l_ws[b*NH + h0 + lane], lacc);
  __syncthreads();
  float a2[HPB][3];
#pragma unroll
  for (int hh = 0; hh < HPB; ++hh)
#pragma unroll
    for (int i = 0; i < 3; ++i) a2[hh][i] = 0.f;
  for (int s = 0; s < CS; ++s) {
    float pv[HPB];
#pragma unroll
    for (int hh = 0; hh < HPB; ++hh) pv[hh] = pl[s*HPB + hh];
    float xv[3];
#pragma unroll
    for (int i = 0; i < 3; ++i)
      xv[i] = x[xbase + (size_t)s*DM + t + 256*i];
#pragma unroll
    for (int hh = 0; hh < HPB; ++hh)
#pragma unroll
      for (int i = 0; i < 3; ++i) a2[hh][i] += pv[hh]*xv[i];
  }
#pragma unroll
  for (int hh = 0; hh < HPB; ++hh)
#pragma unroll
    for (int i = 0; i < 3; ++i)
      atomicAdd(&xw_ws[((size_t)b*NH + h0 + hh)*DM + t + 256*i], a2[hh][i]);
}

extern "C" void kernel_launch(void* const* d_in, const int* in_sizes, int n_in,
                              void* d_out, int out_size, void* d_ws, size_t ws_size,
                              hipStream_t stream) {
  const float* x   = (const float*)d_in[0];
  const float* wqg = (const float*)d_in[7];
  const float* bqg = (const float*)d_in[8];
  const float* wkg = (const float*)d_in[9];
  const float* bkg = (const float*)d_in[10];
  const float* wvg = (const float*)d_in[11];
  const float* bvg = (const float*)d_in[12];
  const float* wo  = (const float*)d_in[13];
  const float* bo  = (const float*)d_in[14];
  const float* wp  = (const float*)d_in[15];
  const float* bp  = (const float*)d_in[16];
  const float* wfc = (const float*)d_in[17];
  const float* bfc = (const float*)d_in[18];

  float* ws        = (float*)d_ws;
  float* qw        = ws;             // 18432
  float* qb        = ws + 18432;     // 24
  float* l         = ws + 18456;     // 24
  float* xw        = ws + 18480;     // 18432
  float* out0      = ws + 36912;     // 1536
  float* attnraw   = ws + 38448;     // 1536
  float* pooledraw = ws + 39984;     // 1536  (out0..pooledraw contiguous = 4608)
  float* part      = ws + 41520;     // 4,718,592 floats (18.9 MB), float4-aligned

  const size_t need_bytes = (size_t)(41520 + (size_t)BB*NH*MCHUNK*DM) * sizeof(float);

  kA<<<dim3(NH, BB, JSA), 256, 0, stream>>>(x, wqg, bqg, wkg, bkg, qw, qb, l, xw, out0);
  if (ws_size >= need_bytes) {
    kBp<<<dim3(MCHUNK, BB), 256, 0, stream>>>(x, qw, qb, l, part);
    kR <<<dim3(NH, BB, 32), 256, 0, stream>>>(part, xw);
  } else {
    kB <<<dim3(NCHUNK, BB, HG), 256, 0, stream>>>(x, qw, qb, l, xw);
  }
  kE1<<<dim3(NH, BB), 256, 0, stream>>>(xw, l, wvg, bvg, out0, attnraw);
  kT <<<dim3(JT),    192, 0, stream>>>(out0, nullptr, wo, attnraw);
  kT <<<dim3(JT),    192, 0, stream>>>(attnraw, bo, wp, pooledraw);
  kT3<<<dim3(8, BB), 256, 0, stream>>>(pooledraw, bp, wfc, bfc, (float*)d_out);
}

// Round 12
// 169.062 us; speedup vs baseline: 1.3580x; 1.0826x over previous
//
#include <hip/hip_runtime.h>

#define BB 2
#define SS 4096
#define DM 768
#define NH 12
#define OUTC 512
#define QSCALE 0.125f

// partial-buffer stage-B geometry (round-6 proven optimum)
#define MCHUNK 256        // s-chunks per batch
#define MCS 16            // s-rows per chunk
// kA geometry
#define JSA 4
#define JWA (DM/JSA)      // 192
// tail geometry (round-6 proven: 64 blocks x 12 rows)
#define JT 64
#define JR (DM/JT)        // 12
// fallback kB geometry (round-1 proven)
#define NCHUNK 128
#define CS 32
#define HPB 3
#define HG (NH/HPB)

// part layout (floats): part[((b*MCHUNK + c)*NH + h)*DM + d]   (round-4 proven)
#define PIDX(b,c,h) (((size_t)((b)*MCHUNK + (c))*NH + (h))*DM)

__device__ __forceinline__ float wave_sum64(float v) {
#pragma unroll
  for (int o = 32; o > 0; o >>= 1) v += __shfl_xor(v, o, 64);
  return v;
}

// Kernel A: per (h,b,js): qg0 = (x[b,0,:]@wqg+bqg)*QSCALE (redundant per js);
// fold wkg into qw[b,h,js-slice] and qb[b,h]. Zero l + xw + out0..pooledraw region.
__global__ __launch_bounds__(256) void kA(const float* __restrict__ x,
    const float* __restrict__ wqg, const float* __restrict__ bqg,
    const float* __restrict__ wkg, const float* __restrict__ bkg,
    float* __restrict__ qw_ws, float* __restrict__ qb_ws,
    float* __restrict__ l_ws, float* __restrict__ xw_ws,
    float* __restrict__ zb /* out0 base: 4608 floats contiguous */) {
  int h = blockIdx.x, b = blockIdx.y, js = blockIdx.z, t = threadIdx.x;
  __shared__ float x0[DM];
  __shared__ float4 red4[16][16];
  __shared__ float qg0[64];
  for (int i = t; i < DM; i += 256) x0[i] = x[(size_t)b*SS*DM + i];
  for (int i = t; i < JWA; i += 256)
    xw_ws[((size_t)b*NH + h)*DM + js*JWA + i] = 0.f;
  if (js == 3 && t < 192) zb[(b*NH + h)*192 + t] = 0.f;   // 24 blk x 192 = 4608
  if (js == 0 && t == 0) l_ws[b*NH + h] = 0.f;
  __syncthreads();
  {
    int cq = t & 15, jg = t >> 4;
    const float4* wq4 = (const float4*)wqg;
    float4 a = {0,0,0,0};
#pragma unroll 8
    for (int jo = 0; jo < 48; ++jo) {
      int j = jg*48 + jo;
      float xv = x0[j];
      float4 wv = wq4[(size_t)j*(DM/4) + h*16 + cq];
      a.x += xv*wv.x; a.y += xv*wv.y; a.z += xv*wv.z; a.w += xv*wv.w;
    }
    red4[jg][cq] = a;
  }
  __syncthreads();
  if (t < 16) {
    float4 a = {0,0,0,0};
#pragma unroll
    for (int jg = 0; jg < 16; ++jg) {
      float4 r = red4[jg][t];
      a.x += r.x; a.y += r.y; a.z += r.z; a.w += r.w;
    }
    float4 bq = ((const float4*)(bqg + h*64))[t];
    a.x = (a.x + bq.x)*QSCALE; a.y = (a.y + bq.y)*QSCALE;
    a.z = (a.z + bq.z)*QSCALE; a.w = (a.w + bq.w)*QSCALE;
    ((float4*)qg0)[t] = a;
  }
  __syncthreads();
  if (js == 0 && t < 64) {
    float v = wave_sum64(qg0[t] * bkg[h*64 + t]);
    if (t == 0) qb_ws[b*NH + h] = v;
  }
  const float4* qg4 = (const float4*)qg0;
  for (int jj = t; jj < JWA; jj += 256) {
    int j = js*JWA + jj;
    const float4* wr = (const float4*)(wkg + (size_t)j*DM + h*64);
    float acc = 0.f;
#pragma unroll
    for (int q = 0; q < 16; ++q) {
      float4 wv = wr[q], qv = qg4[q];
      acc += wv.x*qv.x + wv.y*qv.y + wv.z*qv.z + wv.w*qv.w;
    }
    qw_ws[((size_t)b*NH + h)*DM + j] = acc;
  }
}

// Kernel Bp (round-6 proven): per (chunk,b): 16 rows x 12 heads.
// Phase 1: scores+exp+l(atomic). Phase 2: p-weighted x partial -> PLAIN float4
// stores into private part slot. No xw atomics.
__global__ __launch_bounds__(256) void kBp(const float* __restrict__ x,
    const float* __restrict__ qw_ws, const float* __restrict__ qb_ws,
    float* __restrict__ l_ws, float* __restrict__ part) {
  const int chunk = blockIdx.x, b = blockIdx.y;
  const int t = threadIdx.x, lane = t & 63, w = t >> 6;
  __shared__ alignas(16) float qw[NH*DM];   // 36 KB
  __shared__ float qb[NH];
  __shared__ alignas(16) float pl[MCS*NH];  // 768 B
  __shared__ float lred[4][NH];
  const float4* qwsrc = (const float4*)(qw_ws + (size_t)b*NH*DM);
  float4* qw4s = (float4*)qw;
#pragma unroll
  for (int i = 0; i < 9; ++i) qw4s[t + 256*i] = qwsrc[t + 256*i];
  if (t < NH) qb[t] = qb_ws[b*NH + t];
  __syncthreads();
  const size_t xbase = ((size_t)b*SS + (size_t)chunk*MCS) * DM;
  const float4* x4 = (const float4*)(x + xbase);
  const float4* qw4 = (const float4*)qw;
  const int sl = w*4;
  float acc[4][NH];
#pragma unroll
  for (int si = 0; si < 4; ++si)
#pragma unroll
    for (int hh = 0; hh < NH; ++hh) acc[si][hh] = 0.f;
#pragma unroll
  for (int k = 0; k < 3; ++k) {
    int jq = k*64 + lane;
    float4 xf[4];
#pragma unroll
    for (int si = 0; si < 4; ++si)
      xf[si] = x4[(size_t)(sl + si)*192 + jq];
#pragma unroll
    for (int hh = 0; hh < NH; ++hh) {
      float4 qv = qw4[hh*192 + jq];
#pragma unroll
      for (int si = 0; si < 4; ++si)
        acc[si][hh] += xf[si].x*qv.x + xf[si].y*qv.y + xf[si].z*qv.z + xf[si].w*qv.w;
    }
  }
  float lacc = 0.f, preg = 0.f;
#pragma unroll
  for (int si = 0; si < 4; ++si)
#pragma unroll
    for (int hh = 0; hh < NH; ++hh) {
      float r = wave_sum64(acc[si][hh]);
      float pp = __expf(r + qb[hh]);
      if (lane == hh) lacc += pp;
      if (lane == si*NH + hh) preg = pp;
    }
  if (lane < 4*NH) pl[sl*NH + lane] = preg;   // rows sl..sl+3, heads 0..11
  if (lane < NH) lred[w][lane] = lacc;
  __syncthreads();
  if (t < NH)
    atomicAdd(&l_ws[b*NH + t], lred[0][t] + lred[1][t] + lred[2][t] + lred[3][t]);
  // phase 2: partial xw for this chunk, x rows L1-hot from phase 1
  if (t < 192) {
    float4 a2[NH];
#pragma unroll
    for (int hh = 0; hh < NH; ++hh) a2[hh] = make_float4(0.f,0.f,0.f,0.f);
    for (int s = 0; s < MCS; ++s) {
      float4 xv = x4[s*192 + t];
      const float4* p4 = (const float4*)(pl + s*NH);
      float4 p0 = p4[0], p1 = p4[1], p2 = p4[2];
      float pv[NH] = {p0.x,p0.y,p0.z,p0.w, p1.x,p1.y,p1.z,p1.w, p2.x,p2.y,p2.z,p2.w};
#pragma unroll
      for (int hh = 0; hh < NH; ++hh) {
        a2[hh].x += pv[hh]*xv.x; a2[hh].y += pv[hh]*xv.y;
        a2[hh].z += pv[hh]*xv.z; a2[hh].w += pv[hh]*xv.w;
      }
    }
    float4* pdst = (float4*)part;
    const size_t base = PIDX(b, chunk, 0)/4;      // contiguous 36 KB per chunk
#pragma unroll
    for (int hh = 0; hh < NH; ++hh)
      pdst[base + (size_t)hh*192 + t] = a2[hh];
  }
}

// Kernel R: parallel chunk-reduction of part into xw. Grid (NH, BB, 32):
// z = js*8 + cs; each block sums 32 chunks of a 192-float slice, one atomicAdd/elem.
__global__ __launch_bounds__(256) void kR(const float* __restrict__ part,
    float* __restrict__ xw_ws) {
  int h = blockIdx.x, b = blockIdx.y, z = blockIdx.z, t = threadIdx.x;
  int js = z >> 3, cs = z & 7;
  if (t < 192) {
    const float* src = part + PIDX(b, cs*32, h) + js*192 + t;
    float s0 = 0.f, s1 = 0.f, s2 = 0.f, s3 = 0.f;
    const size_t cstride = (size_t)NH*DM;
#pragma unroll
    for (int c = 0; c < 32; c += 4) {
      s0 += src[(size_t)(c+0)*cstride];
      s1 += src[(size_t)(c+1)*cstride];
      s2 += src[(size_t)(c+2)*cstride];
      s3 += src[(size_t)(c+3)*cstride];
    }
    atomicAdd(&xw_ws[((size_t)b*NH + h)*DM + js*192 + t], (s0+s1)+(s2+s3));
  }
}

// Kernel E1 (round-1 proven): normalize xw by l, apply wvg, complete-write out0.
// Also zeroes attnraw+pooledraw (zbuf, 3072 floats contiguous).
__global__ __launch_bounds__(256) void kE1(const float* __restrict__ xw_ws,
    const float* __restrict__ l_ws, const float* __restrict__ wvg,
    const float* __restrict__ bvg, float* __restrict__ out0_ws,
    float* __restrict__ zbuf) {
  int h = blockIdx.x, b = blockIdx.y, t = threadIdx.x;
  __shared__ float xws[DM];
  __shared__ float4 red4[16][16];
  int bid = b*NH + h;
  if (t < 128) zbuf[bid*128 + t] = 0.f;
  float inv = 1.f / l_ws[bid];
#pragma unroll
  for (int i = 0; i < 3; ++i) {
    int j = t + 256*i;
    xws[j] = xw_ws[((size_t)b*NH + h)*DM + j] * inv;
  }
  __syncthreads();
  {
    int cq = t & 15, jg = t >> 4;
    const float4* wv4 = (const float4*)wvg;
    float4 a = {0,0,0,0};
#pragma unroll 8
    for (int jo = 0; jo < 48; ++jo) {
      int j = jg*48 + jo;
      float xv = xws[j];
      float4 wv = wv4[(size_t)j*(DM/4) + h*16 + cq];
      a.x += xv*wv.x; a.y += xv*wv.y; a.z += xv*wv.z; a.w += xv*wv.w;
    }
    red4[jg][cq] = a;
  }
  __syncthreads();
  if (t < 16) {
    float4 a = {0,0,0,0};
#pragma unroll
    for (int jg = 0; jg < 16; ++jg) {
      float4 r = red4[jg][t];
      a.x += r.x; a.y += r.y; a.z += r.z; a.w += r.w;
    }
    float4 bv = ((const float4*)(bvg + h*64))[t];
    a.x += bv.x; a.y += bv.y; a.z += bv.z; a.w += bv.w;
    ((float4*)(out0_ws + (size_t)b*DM + h*64))[t] = a;
  }
}

// Tail matvec (768x768), j-split 64-way (12 rows/block), atomic accumulation,
// both batches fused.
__global__ __launch_bounds__(192) void kT(const float* __restrict__ inraw,
    const float* __restrict__ bias, const float* __restrict__ W,
    float* __restrict__ outacc) {
  int jb = blockIdx.x, t = threadIdx.x;
  __shared__ float xs[2][JR];
  int j0 = jb*JR;
  if (t < 2*JR) {
    int bb = t / JR, jj = t % JR;
    float v = inraw[bb*DM + j0 + jj];
    if (bias) v += bias[j0 + jj];
    xs[bb][jj] = v;
  }
  __syncthreads();
  float4 a0 = {0,0,0,0}, a1 = {0,0,0,0};
  const float4* W4 = (const float4*)W;
#pragma unroll
  for (int jj = 0; jj < JR; ++jj) {
    float4 wv = W4[(size_t)(j0 + jj)*192 + t];
    float s0 = xs[0][jj], s1 = xs[1][jj];
    a0.x += s0*wv.x; a0.y += s0*wv.y; a0.z += s0*wv.z; a0.w += s0*wv.w;
    a1.x += s1*wv.x; a1.y += s1*wv.y; a1.z += s1*wv.z; a1.w += s1*wv.w;
  }
  int c = t*4;
  atomicAdd(&outacc[c+0], a0.x); atomicAdd(&outacc[c+1], a0.y);
  atomicAdd(&outacc[c+2], a0.z); atomicAdd(&outacc[c+3], a0.w);
  atomicAdd(&outacc[DM+c+0], a1.x); atomicAdd(&outacc[DM+c+1], a1.y);
  atomicAdd(&outacc[DM+c+2], a1.z); atomicAdd(&outacc[DM+c+3], a1.w);
}

// Final: out[b][tile*64+c] = tanh(pooledraw[b]+bp) . wfc[:,c] + bfc[c], complete write.
__global__ __launch_bounds__(256) void kT3(const float* __restrict__ pooledraw,
    const float* __restrict__ bp, const float* __restrict__ wfc,
    const float* __restrict__ bfc, float* __restrict__ out) {
  int tile = blockIdx.x, b = blockIdx.y, t = threadIdx.x;
  __shared__ float pls[DM];
  __shared__ float4 red4[16][16];
  for (int i = t; i < DM; i += 256) pls[i] = tanhf(pooledraw[b*DM + i] + bp[i]);
  __syncthreads();
  {
    int cq = t & 15, jg = t >> 4;
    const float4* w4 = (const float4*)wfc;
    float4 a = {0,0,0,0};
#pragma unroll 8
    for (int jo = 0; jo < 48; ++jo) {
      int j = jg*48 + jo;
      float pv = pls[j];
      float4 wv = w4[(size_t)j*(OUTC/4) + tile*16 + cq];
      a.x += pv*wv.x; a.y += pv*wv.y; a.z += pv*wv.z; a.w += pv*wv.w;
    }
    red4[jg][cq] = a;
  }
  __syncthreads();
  if (t < 16) {
    float4 a = {0,0,0,0};
#pragma unroll
    for (int jg = 0; jg < 16; ++jg) {
      float4 r = red4[jg][t];
      a.x += r.x; a.y += r.y; a.z += r.z; a.w += r.w;
    }
    float4 bf = ((const float4*)(bfc + tile*64))[t];
    a.x += bf.x; a.y += bf.y; a.z += bf.z; a.w += bf.w;
    ((float4*)(out + (size_t)b*OUTC + tile*64))[t] = a;
  }
}

// ============ fallback stage-B (round-1 proven, used if ws too small) ============

__global__ __launch_bounds__(256) void kB(const float* __restrict__ x,
    const float* __restrict__ qw_ws, const float* __restrict__ qb_ws,
    float* __restrict__ l_ws, float* __restrict__ xw_ws) {
  int chunk = blockIdx.x, b = blockIdx.y, h0 = blockIdx.z * HPB;
  int t = threadIdx.x, lane = t & 63, w = t >> 6;
  __shared__ alignas(16) float qw[HPB*DM];
  __shared__ float qb[HPB];
  __shared__ alignas(16) float pl[CS*HPB];
  for (int i = t; i < HPB*DM; i += 256) qw[i] = qw_ws[((size_t)b*NH + h0)*DM + i];
  if (t < HPB) qb[t] = qb_ws[b*NH + h0 + t];
  __syncthreads();
  const size_t xbase = ((size_t)b*SS + chunk*CS) * DM;
  const float4* x4 = (const float4*)(x + xbase);
  const float4* qw4 = (const float4*)qw;
  float lacc = 0.f;
  for (int batch = 0; batch < 2; ++batch) {
    int sl = w*8 + batch*4;
    float acc[4][HPB];
#pragma unroll
    for (int si = 0; si < 4; ++si)
#pragma unroll
      for (int hh = 0; hh < HPB; ++hh) acc[si][hh] = 0.f;
#pragma unroll
    for (int k = 0; k < 3; ++k) {
      int jq = k*64 + lane;
      float4 xf[4];
#pragma unroll
      for (int si = 0; si < 4; ++si)
        xf[si] = x4[(size_t)(sl + si)*192 + jq];
#pragma unroll
      for (int hh = 0; hh < HPB; ++hh) {
        float4 qv = qw4[hh*192 + jq];
#pragma unroll
        for (int si = 0; si < 4; ++si)
          acc[si][hh] += xf[si].x*qv.x + xf[si].y*qv.y + xf[si].z*qv.z + xf[si].w*qv.w;
      }
    }
    float preg = 0.f;
#pragma unroll
    for (int si = 0; si < 4; ++si)
#pragma unroll
      for (int hh = 0; hh < HPB; ++hh) {
        float r = wave_sum64(acc[si][hh]);
        float pp = __expf(r + qb[hh]);
        if (lane == hh) lacc += pp;
        if (lane == si*HPB + hh) preg = pp;
      }
    if (lane < 4*HPB) pl[(sl + lane/HPB)*HPB + (lane % HPB)] = preg;
  }
  if (lane < HPB) atomicAdd(&l_ws[b*NH + h0 + lane], lacc);
  __syncthreads();
  float a2[HPB][3];
#pragma unroll
  for (int hh = 0; hh < HPB; ++hh)
#pragma unroll
    for (int i = 0; i < 3; ++i) a2[hh][i] = 0.f;
  for (int s = 0; s < CS; ++s) {
    float pv[HPB];
#pragma unroll
    for (int hh = 0; hh < HPB; ++hh) pv[hh] = pl[s*HPB + hh];
    float xv[3];
#pragma unroll
    for (int i = 0; i < 3; ++i)
      xv[i] = x[xbase + (size_t)s*DM + t + 256*i];
#pragma unroll
    for (int hh = 0; hh < HPB; ++hh)
#pragma unroll
      for (int i = 0; i < 3; ++i) a2[hh][i] += pv[hh]*xv[i];
  }
#pragma unroll
  for (int hh = 0; hh < HPB; ++hh)
#pragma unroll
    for (int i = 0; i < 3; ++i)
      atomicAdd(&xw_ws[((size_t)b*NH + h0 + hh)*DM + t + 256*i], a2[hh][i]);
}

extern "C" void kernel_launch(void* const* d_in, const int* in_sizes, int n_in,
                              void* d_out, int out_size, void* d_ws, size_t ws_size,
                              hipStream_t stream) {
  const float* x   = (const float*)d_in[0];
  const float* wqg = (const float*)d_in[7];
  const float* bqg = (const float*)d_in[8];
  const float* wkg = (const float*)d_in[9];
  const float* bkg = (const float*)d_in[10];
  const float* wvg = (const float*)d_in[11];
  const float* bvg = (const float*)d_in[12];
  const float* wo  = (const float*)d_in[13];
  const float* bo  = (const float*)d_in[14];
  const float* wp  = (const float*)d_in[15];
  const float* bp  = (const float*)d_in[16];
  const float* wfc = (const float*)d_in[17];
  const float* bfc = (const float*)d_in[18];

  float* ws        = (float*)d_ws;
  float* qw        = ws;             // 18432
  float* qb        = ws + 18432;     // 24
  float* l         = ws + 18456;     // 24
  float* xw        = ws + 18480;     // 18432
  float* out0      = ws + 36912;     // 1536
  float* attnraw   = ws + 38448;     // 1536
  float* pooledraw = ws + 39984;     // 1536  (out0..pooledraw contiguous = 4608)
  float* part      = ws + 41520;     // 4,718,592 floats (18.9 MB), float4-aligned

  const size_t need_bytes = (size_t)(41520 + (size_t)BB*NH*MCHUNK*DM) * sizeof(float);

  kA<<<dim3(NH, BB, JSA), 256, 0, stream>>>(x, wqg, bqg, wkg, bkg, qw, qb, l, xw, out0);
  if (ws_size >= need_bytes) {
    kBp<<<dim3(MCHUNK, BB), 256, 0, stream>>>(x, qw, qb, l, part);
    kR <<<dim3(NH, BB, 32), 256, 0, stream>>>(part, xw);
  } else {
    kB <<<dim3(NCHUNK, BB, HG), 256, 0, stream>>>(x, qw, qb, l, xw);
  }
  kE1<<<dim3(NH, BB), 256, 0, stream>>>(xw, l, wvg, bvg, out0, attnraw);
  kT <<<dim3(JT),    192, 0, stream>>>(out0, nullptr, wo, attnraw);
  kT <<<dim3(JT),    192, 0, stream>>>(attnraw, bo, wp, pooledraw);
  kT3<<<dim3(8, BB), 256, 0, stream>>>(pooledraw, bp, wfc, bfc, (float*)d_out);
}

// Round 13
// 166.889 us; speedup vs baseline: 1.3757x; 1.0130x over previous
//
#include <hip/hip_runtime.h>

#define BB 2
#define SS 4096
#define DM 768
#define NH 12
#define OUTC 512
#define QSCALE 0.125f

// partial-buffer stage-B geometry (round-6 proven optimum)
#define MCHUNK 256        // s-chunks per batch
#define MCS 16            // s-rows per chunk
// kA geometry
#define JSA 4
#define JWA (DM/JSA)      // 192
// tail geometry (round-6 proven: 64 blocks x 12 rows)
#define JT 64
#define JR (DM/JT)        // 12
// fallback kB geometry (round-1 proven)
#define NCHUNK 128
#define CS 32
#define HPB 3
#define HG (NH/HPB)

// part layout (floats): part[((b*MCHUNK + c)*NH + h)*DM + d]   (round-4 proven)
#define PIDX(b,c,h) (((size_t)((b)*MCHUNK + (c))*NH + (h))*DM)

__device__ __forceinline__ float wave_sum64(float v) {
#pragma unroll
  for (int o = 32; o > 0; o >>= 1) v += __shfl_xor(v, o, 64);
  return v;
}

// Kernel A: per (h,b,js): qg0 = (x[b,0,:]@wqg+bqg)*QSCALE (redundant per js);
// fold wkg into qw[b,h,js-slice] and qb[b,h]. Zero l + xw + out0..pooledraw region.
__global__ __launch_bounds__(256) void kA(const float* __restrict__ x,
    const float* __restrict__ wqg, const float* __restrict__ bqg,
    const float* __restrict__ wkg, const float* __restrict__ bkg,
    float* __restrict__ qw_ws, float* __restrict__ qb_ws,
    float* __restrict__ l_ws, float* __restrict__ xw_ws,
    float* __restrict__ zb /* out0 base: 4608 floats contiguous */) {
  int h = blockIdx.x, b = blockIdx.y, js = blockIdx.z, t = threadIdx.x;
  __shared__ float x0[DM];
  __shared__ float4 red4[16][16];
  __shared__ float qg0[64];
  for (int i = t; i < DM; i += 256) x0[i] = x[(size_t)b*SS*DM + i];
  for (int i = t; i < JWA; i += 256)
    xw_ws[((size_t)b*NH + h)*DM + js*JWA + i] = 0.f;
  if (js == 3 && t < 192) zb[(b*NH + h)*192 + t] = 0.f;   // 24 blk x 192 = 4608
  if (js == 0 && t == 0) l_ws[b*NH + h] = 0.f;
  __syncthreads();
  {
    int cq = t & 15, jg = t >> 4;
    const float4* wq4 = (const float4*)wqg;
    float4 a = {0,0,0,0};
#pragma unroll 8
    for (int jo = 0; jo < 48; ++jo) {
      int j = jg*48 + jo;
      float xv = x0[j];
      float4 wv = wq4[(size_t)j*(DM/4) + h*16 + cq];
      a.x += xv*wv.x; a.y += xv*wv.y; a.z += xv*wv.z; a.w += xv*wv.w;
    }
    red4[jg][cq] = a;
  }
  __syncthreads();
  if (t < 16) {
    float4 a = {0,0,0,0};
#pragma unroll
    for (int jg = 0; jg < 16; ++jg) {
      float4 r = red4[jg][t];
      a.x += r.x; a.y += r.y; a.z += r.z; a.w += r.w;
    }
    float4 bq = ((const float4*)(bqg + h*64))[t];
    a.x = (a.x + bq.x)*QSCALE; a.y = (a.y + bq.y)*QSCALE;
    a.z = (a.z + bq.z)*QSCALE; a.w = (a.w + bq.w)*QSCALE;
    ((float4*)qg0)[t] = a;
  }
  __syncthreads();
  if (js == 0 && t < 64) {
    float v = wave_sum64(qg0[t] * bkg[h*64 + t]);
    if (t == 0) qb_ws[b*NH + h] = v;
  }
  const float4* qg4 = (const float4*)qg0;
  for (int jj = t; jj < JWA; jj += 256) {
    int j = js*JWA + jj;
    const float4* wr = (const float4*)(wkg + (size_t)j*DM + h*64);
    float acc = 0.f;
#pragma unroll
    for (int q = 0; q < 16; ++q) {
      float4 wv = wr[q], qv = qg4[q];
      acc += wv.x*qv.x + wv.y*qv.y + wv.z*qv.z + wv.w*qv.w;
    }
    qw_ws[((size_t)b*NH + h)*DM + j] = acc;
  }
}

// Kernel Br: register-phase-2 stage B. Per (chunk,b): 16 rows x 12 heads.
// Phase 1: per wave, 4 row-batches; after each wave_sum64 the broadcast pp is
// FMA'd into per-lane a2[12][3] float4 accumulators (no x re-read, no pl).
// Cross-wave reduce via two 36KB LDS buffers (qw buffer reused), then all 256
// threads merge+store to part. __launch_bounds__(256,2) caps VGPR at 256 (need
// ~190) -- guards against the round-2/3 spill failure mode.
__global__ __launch_bounds__(256, 2) void kBr(const float* __restrict__ x,
    const float* __restrict__ qw_ws, const float* __restrict__ qb_ws,
    float* __restrict__ l_ws, float* __restrict__ part) {
  const int chunk = blockIdx.x, b = blockIdx.y;
  const int t = threadIdx.x, lane = t & 63, w = t >> 6;
  __shared__ alignas(16) float qwbuf[NH*DM];  // 36 KB: qw, then reduce buf0
  __shared__ alignas(16) float red1[NH*DM];   // 36 KB: reduce buf1
  __shared__ float qb[NH];
  __shared__ float lred[4][NH];
  const float4* qwsrc = (const float4*)(qw_ws + (size_t)b*NH*DM);
  float4* qw4s = (float4*)qwbuf;
#pragma unroll
  for (int i = 0; i < 9; ++i) qw4s[t + 256*i] = qwsrc[t + 256*i];
  if (t < NH) qb[t] = qb_ws[b*NH + t];
  __syncthreads();
  const size_t xbase = ((size_t)b*SS + (size_t)chunk*MCS) * DM;
  const float4* x4 = (const float4*)(x + xbase);
  const float4* qw4 = (const float4*)qwbuf;
  const int sl = w*4;
  float4 a2[NH][3];
#pragma unroll
  for (int hh = 0; hh < NH; ++hh)
#pragma unroll
    for (int k = 0; k < 3; ++k) a2[hh][k] = make_float4(0.f,0.f,0.f,0.f);
  float lacc = 0.f;
#pragma unroll
  for (int si = 0; si < 4; ++si) {
    float4 xf[3];
#pragma unroll
    for (int k = 0; k < 3; ++k)
      xf[k] = x4[(size_t)(sl + si)*192 + k*64 + lane];
    float acc[NH];
#pragma unroll
    for (int hh = 0; hh < NH; ++hh) acc[hh] = 0.f;
#pragma unroll
    for (int k = 0; k < 3; ++k)
#pragma unroll
      for (int hh = 0; hh < NH; ++hh) {
        float4 qv = qw4[hh*192 + k*64 + lane];
        acc[hh] += xf[k].x*qv.x + xf[k].y*qv.y + xf[k].z*qv.z + xf[k].w*qv.w;
      }
#pragma unroll
    for (int hh = 0; hh < NH; ++hh) {
      float r = wave_sum64(acc[hh]);       // broadcast in all lanes
      float pp = __expf(r + qb[hh]);
      if (lane == hh) lacc += pp;
#pragma unroll
      for (int k = 0; k < 3; ++k) {
        a2[hh][k].x += pp*xf[k].x; a2[hh][k].y += pp*xf[k].y;
        a2[hh][k].z += pp*xf[k].z; a2[hh][k].w += pp*xf[k].w;
      }
    }
  }
  if (lane < NH) lred[w][lane] = lacc;
  __syncthreads();   // phase 1 done for ALL waves; qwbuf now reusable
  if (t < NH)
    atomicAdd(&l_ws[b*NH + t], lred[0][t] + lred[1][t] + lred[2][t] + lred[3][t]);
  // cross-wave reduce: waves 0/1 write buf0/buf1; waves 2/3 add into them
  float4* buf0 = (float4*)qwbuf;
  float4* buf1 = (float4*)red1;
  if (w == 0) {
#pragma unroll
    for (int hh = 0; hh < NH; ++hh)
#pragma unroll
      for (int k = 0; k < 3; ++k) buf0[hh*192 + k*64 + lane] = a2[hh][k];
  } else if (w == 1) {
#pragma unroll
    for (int hh = 0; hh < NH; ++hh)
#pragma unroll
      for (int k = 0; k < 3; ++k) buf1[hh*192 + k*64 + lane] = a2[hh][k];
  }
  __syncthreads();
  if (w == 2) {
#pragma unroll
    for (int hh = 0; hh < NH; ++hh)
#pragma unroll
      for (int k = 0; k < 3; ++k) {
        int idx = hh*192 + k*64 + lane;
        float4 v = buf0[idx];
        v.x += a2[hh][k].x; v.y += a2[hh][k].y;
        v.z += a2[hh][k].z; v.w += a2[hh][k].w;
        buf0[idx] = v;
      }
  } else if (w == 3) {
#pragma unroll
    for (int hh = 0; hh < NH; ++hh)
#pragma unroll
      for (int k = 0; k < 3; ++k) {
        int idx = hh*192 + k*64 + lane;
        float4 v = buf1[idx];
        v.x += a2[hh][k].x; v.y += a2[hh][k].y;
        v.z += a2[hh][k].z; v.w += a2[hh][k].w;
        buf1[idx] = v;
      }
  }
  __syncthreads();
  // merge buf0+buf1, store to part (2304 float4, 9 per thread, coalesced)
  float4* pdst = (float4*)part;
  const size_t base = PIDX(b, chunk, 0)/4;
#pragma unroll
  for (int i = 0; i < 9; ++i) {
    int idx = t + 256*i;
    float4 v0 = buf0[idx], v1 = buf1[idx];
    v0.x += v1.x; v0.y += v1.y; v0.z += v1.z; v0.w += v1.w;
    pdst[base + idx] = v0;
  }
}

// Kernel R: parallel chunk-reduction of part into xw. Grid (NH, BB, 32):
// z = js*8 + cs; each block sums 32 chunks of a 192-float slice, one atomicAdd/elem.
__global__ __launch_bounds__(256) void kR(const float* __restrict__ part,
    float* __restrict__ xw_ws) {
  int h = blockIdx.x, b = blockIdx.y, z = blockIdx.z, t = threadIdx.x;
  int js = z >> 3, cs = z & 7;
  if (t < 192) {
    const float* src = part + PIDX(b, cs*32, h) + js*192 + t;
    float s0 = 0.f, s1 = 0.f, s2 = 0.f, s3 = 0.f;
    const size_t cstride = (size_t)NH*DM;
#pragma unroll
    for (int c = 0; c < 32; c += 4) {
      s0 += src[(size_t)(c+0)*cstride];
      s1 += src[(size_t)(c+1)*cstride];
      s2 += src[(size_t)(c+2)*cstride];
      s3 += src[(size_t)(c+3)*cstride];
    }
    atomicAdd(&xw_ws[((size_t)b*NH + h)*DM + js*192 + t], (s0+s1)+(s2+s3));
  }
}

// Kernel E1 (round-1 proven): normalize xw by l, apply wvg, complete-write out0.
// Also zeroes attnraw+pooledraw (zbuf, 3072 floats contiguous).
__global__ __launch_bounds__(256) void kE1(const float* __restrict__ xw_ws,
    const float* __restrict__ l_ws, const float* __restrict__ wvg,
    const float* __restrict__ bvg, float* __restrict__ out0_ws,
    float* __restrict__ zbuf) {
  int h = blockIdx.x, b = blockIdx.y, t = threadIdx.x;
  __shared__ float xws[DM];
  __shared__ float4 red4[16][16];
  int bid = b*NH + h;
  if (t < 128) zbuf[bid*128 + t] = 0.f;
  float inv = 1.f / l_ws[bid];
#pragma unroll
  for (int i = 0; i < 3; ++i) {
    int j = t + 256*i;
    xws[j] = xw_ws[((size_t)b*NH + h)*DM + j] * inv;
  }
  __syncthreads();
  {
    int cq = t & 15, jg = t >> 4;
    const float4* wv4 = (const float4*)wvg;
    float4 a = {0,0,0,0};
#pragma unroll 8
    for (int jo = 0; jo < 48; ++jo) {
      int j = jg*48 + jo;
      float xv = xws[j];
      float4 wv = wv4[(size_t)j*(DM/4) + h*16 + cq];
      a.x += xv*wv.x; a.y += xv*wv.y; a.z += xv*wv.z; a.w += xv*wv.w;
    }
    red4[jg][cq] = a;
  }
  __syncthreads();
  if (t < 16) {
    float4 a = {0,0,0,0};
#pragma unroll
    for (int jg = 0; jg < 16; ++jg) {
      float4 r = red4[jg][t];
      a.x += r.x; a.y += r.y; a.z += r.z; a.w += r.w;
    }
    float4 bv = ((const float4*)(bvg + h*64))[t];
    a.x += bv.x; a.y += bv.y; a.z += bv.z; a.w += bv.w;
    ((float4*)(out0_ws + (size_t)b*DM + h*64))[t] = a;
  }
}

// Tail matvec (768x768), j-split 64-way (12 rows/block), atomic accumulation,
// both batches fused.
__global__ __launch_bounds__(192) void kT(const float* __restrict__ inraw,
    const float* __restrict__ bias, const float* __restrict__ W,
    float* __restrict__ outacc) {
  int jb = blockIdx.x, t = threadIdx.x;
  __shared__ float xs[2][JR];
  int j0 = jb*JR;
  if (t < 2*JR) {
    int bb = t / JR, jj = t % JR;
    float v = inraw[bb*DM + j0 + jj];
    if (bias) v += bias[j0 + jj];
    xs[bb][jj] = v;
  }
  __syncthreads();
  float4 a0 = {0,0,0,0}, a1 = {0,0,0,0};
  const float4* W4 = (const float4*)W;
#pragma unroll
  for (int jj = 0; jj < JR; ++jj) {
    float4 wv = W4[(size_t)(j0 + jj)*192 + t];
    float s0 = xs[0][jj], s1 = xs[1][jj];
    a0.x += s0*wv.x; a0.y += s0*wv.y; a0.z += s0*wv.z; a0.w += s0*wv.w;
    a1.x += s1*wv.x; a1.y += s1*wv.y; a1.z += s1*wv.z; a1.w += s1*wv.w;
  }
  int c = t*4;
  atomicAdd(&outacc[c+0], a0.x); atomicAdd(&outacc[c+1], a0.y);
  atomicAdd(&outacc[c+2], a0.z); atomicAdd(&outacc[c+3], a0.w);
  atomicAdd(&outacc[DM+c+0], a1.x); atomicAdd(&outacc[DM+c+1], a1.y);
  atomicAdd(&outacc[DM+c+2], a1.z); atomicAdd(&outacc[DM+c+3], a1.w);
}

// Final: out[b][tile*64+c] = tanh(pooledraw[b]+bp) . wfc[:,c] + bfc[c], complete write.
__global__ __launch_bounds__(256) void kT3(const float* __restrict__ pooledraw,
    const float* __restrict__ bp, const float* __restrict__ wfc,
    const float* __restrict__ bfc, float* __restrict__ out) {
  int tile = blockIdx.x, b = blockIdx.y, t = threadIdx.x;
  __shared__ float pls[DM];
  __shared__ float4 red4[16][16];
  for (int i = t; i < DM; i += 256) pls[i] = tanhf(pooledraw[b*DM + i] + bp[i]);
  __syncthreads();
  {
    int cq = t & 15, jg = t >> 4;
    const float4* w4 = (const float4*)wfc;
    float4 a = {0,0,0,0};
#pragma unroll 8
    for (int jo = 0; jo < 48; ++jo) {
      int j = jg*48 + jo;
      float pv = pls[j];
      float4 wv = w4[(size_t)j*(OUTC/4) + tile*16 + cq];
      a.x += pv*wv.x; a.y += pv*wv.y; a.z += pv*wv.z; a.w += pv*wv.w;
    }
    red4[jg][cq] = a;
  }
  __syncthreads();
  if (t < 16) {
    float4 a = {0,0,0,0};
#pragma unroll
    for (int jg = 0; jg < 16; ++jg) {
      float4 r = red4[jg][t];
      a.x += r.x; a.y += r.y; a.z += r.z; a.w += r.w;
    }
    float4 bf = ((const float4*)(bfc + tile*64))[t];
    a.x += bf.x; a.y += bf.y; a.z += bf.z; a.w += bf.w;
    ((float4*)(out + (size_t)b*OUTC + tile*64))[t] = a;
  }
}

// ============ fallback stage-B (round-1 proven, used if ws too small) ============

__global__ __launch_bounds__(256) void kB(const float* __restrict__ x,
    const float* __restrict__ qw_ws, const float* __restrict__ qb_ws,
    float* __restrict__ l_ws, float* __restrict__ xw_ws) {
  int chunk = blockIdx.x, b = blockIdx.y, h0 = blockIdx.z * HPB;
  int t = threadIdx.x, lane = t & 63, w = t >> 6;
  __shared__ alignas(16) float qw[HPB*DM];
  __shared__ float qb[HPB];
  __shared__ alignas(16) float pl[CS*HPB];
  for (int i = t; i < HPB*DM; i += 256) qw[i] = qw_ws[((size_t)b*NH + h0)*DM + i];
  if (t < HPB) qb[t] = qb_ws[b*NH + h0 + t];
  __syncthreads();
  const size_t xbase = ((size_t)b*SS + chunk*CS) * DM;
  const float4* x4 = (const float4*)(x + xbase);
  const float4* qw4 = (const float4*)qw;
  float lacc = 0.f;
  for (int batch = 0; batch < 2; ++batch) {
    int sl = w*8 + batch*4;
    float acc[4][HPB];
#pragma unroll
    for (int si = 0; si < 4; ++si)
#pragma unroll
      for (int hh = 0; hh < HPB; ++hh) acc[si][hh] = 0.f;
#pragma unroll
    for (int k = 0; k < 3; ++k) {
      int jq = k*64 + lane;
      float4 xf[4];
#pragma unroll
      for (int si = 0; si < 4; ++si)
        xf[si] = x4[(size_t)(sl + si)*192 + jq];
#pragma unroll
      for (int hh = 0; hh < HPB; ++hh) {
        float4 qv = qw4[hh*192 + jq];
#pragma unroll
        for (int si = 0; si < 4; ++si)
          acc[si][hh] += xf[si].x*qv.x + xf[si].y*qv.y + xf[si].z*qv.z + xf[si].w*qv.w;
      }
    }
    float preg = 0.f;
#pragma unroll
    for (int si = 0; si < 4; ++si)
#pragma unroll
      for (int hh = 0; hh < HPB; ++hh) {
        float r = wave_sum64(acc[si][hh]);
        float pp = __expf(r + qb[hh]);
        if (lane == hh) lacc += pp;
        if (lane == si*HPB + hh) preg = pp;
      }
    if (lane < 4*HPB) pl[(sl + lane/HPB)*HPB + (lane % HPB)] = preg;
  }
  if (lane < HPB) atomicAdd(&l_ws[b*NH + h0 + lane], lacc);
  __syncthreads();
  float a2[HPB][3];
#pragma unroll
  for (int hh = 0; hh < HPB; ++hh)
#pragma unroll
    for (int i = 0; i < 3; ++i) a2[hh][i] = 0.f;
  for (int s = 0; s < CS; ++s) {
    float pv[HPB];
#pragma unroll
    for (int hh = 0; hh < HPB; ++hh) pv[hh] = pl[s*HPB + hh];
    float xv[3];
#pragma unroll
    for (int i = 0; i < 3; ++i)
      xv[i] = x[xbase + (size_t)s*DM + t + 256*i];
#pragma unroll
    for (int hh = 0; hh < HPB; ++hh)
#pragma unroll
      for (int i = 0; i < 3; ++i) a2[hh][i] += pv[hh]*xv[i];
  }
#pragma unroll
  for (int hh = 0; hh < HPB; ++hh)
#pragma unroll
    for (int i = 0; i < 3; ++i)
      atomicAdd(&xw_ws[((size_t)b*NH + h0 + hh)*DM + t + 256*i], a2[hh][i]);
}

extern "C" void kernel_launch(void* const* d_in, const int* in_sizes, int n_in,
                              void* d_out, int out_size, void* d_ws, size_t ws_size,
                              hipStream_t stream) {
  const float* x   = (const float*)d_in[0];
  const float* wqg = (const float*)d_in[7];
  const float* bqg = (const float*)d_in[8];
  const float* wkg = (const float*)d_in[9];
  const float* bkg = (const float*)d_in[10];
  const float* wvg = (const float*)d_in[11];
  const float* bvg = (const float*)d_in[12];
  const float* wo  = (const float*)d_in[13];
  const float* bo  = (const float*)d_in[14];
  const float* wp  = (const float*)d_in[15];
  const float* bp  = (const float*)d_in[16];
  const float* wfc = (const float*)d_in[17];
  const float* bfc = (const float*)d_in[18];

  float* ws        = (float*)d_ws;
  float* qw        = ws;             // 18432
  float* qb        = ws + 18432;     // 24
  float* l         = ws + 18456;     // 24
  float* xw        = ws + 18480;     // 18432
  float* out0      = ws + 36912;     // 1536
  float* attnraw   = ws + 38448;     // 1536
  float* pooledraw = ws + 39984;     // 1536  (out0..pooledraw contiguous = 4608)
  float* part      = ws + 41520;     // 4,718,592 floats (18.9 MB), float4-aligned

  const size_t need_bytes = (size_t)(41520 + (size_t)BB*NH*MCHUNK*DM) * sizeof(float);

  kA<<<dim3(NH, BB, JSA), 256, 0, stream>>>(x, wqg, bqg, wkg, bkg, qw, qb, l, xw, out0);
  if (ws_size >= need_bytes) {
    kBr<<<dim3(MCHUNK, BB), 256, 0, stream>>>(x, qw, qb, l, part);
    kR <<<dim3(NH, BB, 32), 256, 0, stream>>>(part, xw);
  } else {
    kB <<<dim3(NCHUNK, BB, HG), 256, 0, stream>>>(x, qw, qb, l, xw);
  }
  kE1<<<dim3(NH, BB), 256, 0, stream>>>(xw, l, wvg, bvg, out0, attnraw);
  kT <<<dim3(JT),    192, 0, stream>>>(out0, nullptr, wo, attnraw);
  kT <<<dim3(JT),    192, 0, stream>>>(attnraw, bo, wp, pooledraw);
  kT3<<<dim3(8, BB), 256, 0, stream>>>(pooledraw, bp, wfc, bfc, (float*)d_out);
}